// Round 11
// baseline (228.297 us; speedup 1.0000x reference)
//
#include <hip/hip_runtime.h>
#include <hip/hip_bf16.h>
#include <hip/hip_fp16.h>

// Problem constants: B=8, IN_C=64, H=W=32, NH=8, dkh=dvh=8, OUT_C=128.
// Inputs: float32 storage (verified R1/R2). Output: float32.
//
// R10->R11: k_prep deleted (1x1 conv needs no padding; conv staging zero-pads
// on the fly; weights/rel tables read direct from d_in). k_out conv: 4 cols x
// 4 oc per thread, 128 blocks -> each weight-b128 serves 16 FMAs; x-tile row
// stride 35 (odd) keeps window reads <=2-way banked (free on wave64).

// ---- workspace layout (float32 element offsets) ----
constexpr int QBUF  = 0;                       // [64 bn][1024][8] f32 (q pre-scaled)
constexpr int KVBUF = 524288;                  // [64 bn][1024][8] uint (f16x2 k|v)
constexpr int APRE  = KVBUF + 524288;          // [8][64][1024]
// total 1.57M floats ~ 6.3 MB

typedef _Float16 h2 __attribute__((ext_vector_type(2)));

#if defined(__has_builtin)
#if __has_builtin(__builtin_amdgcn_fdot2)
#define HAVE_FDOT2 1
#endif
#endif

__device__ __forceinline__ float fdot2_acc(h2 a, h2 b, float c) {
#ifdef HAVE_FDOT2
    return __builtin_amdgcn_fdot2(a, b, c, false);
#else
    return c + (float)a[0] * (float)b[0] + (float)a[1] * (float)b[1];
#endif
}

__device__ __forceinline__ float dot8(float4 a, float4 b, const float* r) {
    return a.x*r[0] + a.y*r[1] + a.z*r[2] + a.w*r[3] +
           b.x*r[4] + b.y*r[5] + b.z*r[6] + b.w*r[7];
}

union KV16 { uint4 u; h2 h[4]; };
union PK16 { __half2 hh; unsigned int u; };

// ---------------------------------------------------------------------------
// Kernel 1: qkv 1x1 conv. grid = 8(b) x 4(pos chunk) x 16(out group of 12).
// Reads x DIRECTLY (no padding needed for 1x1; coalesced: lanes = positions).
// Channel pairs computed then stored immediately (2 acc chains -> no spill).
// Q stored f32 (scaled); K/V stored packed f16x2:
// kvh[(bn*1024+p)*8 + dw]: dw 0..3 = k pairs, 4..7 = v pairs.
// ---------------------------------------------------------------------------
__global__ __launch_bounds__(256) void k_qkv(
    const float* __restrict__ x,
    const float* __restrict__ wq,
    const float* __restrict__ bq,
    float* __restrict__ qbuf,
    unsigned int* __restrict__ kvh)
{
    __shared__ __align__(16) float4 wl4[192];   // 12 rows x 16 float4
    __shared__ float bl[12];

    int blk = blockIdx.x;
    int b = blk >> 6, rem = blk & 63, pc = rem >> 4, og = rem & 15;
    int tid = threadIdx.x;

    if (tid < 192) wl4[tid] = ((const float4*)(wq + og * 768))[tid];
    if (tid < 12)  bl[tid] = bq[og * 12 + tid];

    int p = pc * 256 + tid;                // 0..1023
    const float* xb = x + (b * 64) * 1024 + p;
    float xr[64];
    #pragma unroll
    for (int c = 0; c < 64; ++c) xr[c] = xb[c * 1024];

    __syncthreads();

    for (int pr = 0; pr < 6; ++pr) {       // channel pair (2 chains live)
        int oo = pr * 2;
        float accA = bl[oo], accB = bl[oo + 1];
        #pragma unroll
        for (int c4 = 0; c4 < 16; ++c4) {
            float4 wa = wl4[oo * 16 + c4];        // LDS broadcast
            float4 wb = wl4[(oo + 1) * 16 + c4];
            accA = fmaf(wa.x, xr[c4 * 4 + 0], accA);
            accA = fmaf(wa.y, xr[c4 * 4 + 1], accA);
            accA = fmaf(wa.z, xr[c4 * 4 + 2], accA);
            accA = fmaf(wa.w, xr[c4 * 4 + 3], accA);
            accB = fmaf(wb.x, xr[c4 * 4 + 0], accB);
            accB = fmaf(wb.y, xr[c4 * 4 + 1], accB);
            accB = fmaf(wb.z, xr[c4 * 4 + 2], accB);
            accB = fmaf(wb.w, xr[c4 * 4 + 3], accB);
        }
        int o = og * 12 + oo;              // even; pair never straddles q/k/v
        if (o < 64) {
            float2 qv = make_float2(accA * 0.35355339059327373f,
                                    accB * 0.35355339059327373f);
            *(float2*)(qbuf + ((b * 8 + (o >> 3)) * 1024 + p) * 8 + (o & 7)) = qv;
        } else {
            PK16 pk;
            pk.hh = __floats2half2_rn(accA, accB);
            int idx;
            if (o < 128) {
                int kk = o - 64;
                idx = ((b * 8 + (kk >> 3)) * 1024 + p) * 8 + ((kk & 7) >> 1);
            } else {
                int vv = o - 128;
                idx = ((b * 8 + (vv >> 3)) * 1024 + p) * 8 + 4 + ((vv & 7) >> 1);
            }
            kvh[idx] = pk.u;
        }
    }
}

// ---------------------------------------------------------------------------
// Kernel 2: attention. grid = 64(bn) x 8(query chunk of 128) = 512 blocks.
// Thread (lane, quad) owns queries {iq0, iq0+64}; wave quad owns a 256-key
// quarter staged ONCE into LDS as f16 (8 KB/wave). Inner iter: 2x ds_read_b128
// + 8 fdot2 + 2 exp + 8 pk_fma_f16. Ah in regs; Aw LDS per 32 keys.
// rel tables read directly from inputs. No-max softmax (logits O(+-3)).
// ---------------------------------------------------------------------------
__global__ __launch_bounds__(256) void k_attn(
    const float* __restrict__ qbuf,
    const unsigned int* __restrict__ kvh,
    const float* __restrict__ relw,
    const float* __restrict__ relh,
    float* __restrict__ apre)
{
    // [0,4096): lAw[32][128]; [4096,12288): stage 4 waves x 2048 dwords.
    // After main loop, [0,4608) reused as reduction buffer.
    __shared__ __align__(16) float smem[12288];
    unsigned int* stageAll = (unsigned int*)(smem + 4096);

    int tid = threadIdx.x;
    int lane = tid & 63, quad = tid >> 6;
    int bn = blockIdx.x >> 3, qcv = blockIdx.x & 7;

    // ---- fill lAw: thread covers query qi = tid&127, rows (tid>>7)*16.. ----
    {
        int qi = tid & 127;
        int r0 = (tid >> 7) * 16;
        int iqf = qcv * 128 + qi;
        int wf = iqf & 31;
        const float* qpf = qbuf + (bn * 1024 + iqf) * 8;
        float4 fa = *(const float4*)qpf;
        float4 fb = *(const float4*)(qpf + 4);
        #pragma unroll
        for (int r = r0; r < r0 + 16; ++r)
            smem[r * 128 + qi] = dot8(fa, fb, relw + (r - wf + 31) * 8);
    }

    // ---- stage this wave's key quarter: 256 keys x 8 dwords (f16) ----
    unsigned int* stg = stageAll + quad * 2048;
    {
        const uint4* src = (const uint4*)(kvh + (bn * 1024 + quad * 256) * 8);
        uint4* dst = (uint4*)stg;
        #pragma unroll
        for (int i = 0; i < 8; ++i)
            dst[i * 64 + lane] = src[i * 64 + lane];
    }

    // ---- per-thread queries ----
    int iq0 = qcv * 128 + lane, iq1 = iq0 + 64;
    int h0q = iq0 >> 5, h1q = iq1 >> 5;
    const float* qp0 = qbuf + (bn * 1024 + iq0) * 8;
    const float* qp1 = qbuf + (bn * 1024 + iq1) * 8;
    float4 q0a = *(const float4*)qp0, q0b = *(const float4*)(qp0 + 4);
    float4 q1a = *(const float4*)qp1, q1b = *(const float4*)(qp1 + 4);

    h2 qh0[4], qh1[4];
    qh0[0] = h2{(_Float16)q0a.x, (_Float16)q0a.y};
    qh0[1] = h2{(_Float16)q0a.z, (_Float16)q0a.w};
    qh0[2] = h2{(_Float16)q0b.x, (_Float16)q0b.y};
    qh0[3] = h2{(_Float16)q0b.z, (_Float16)q0b.w};
    qh1[0] = h2{(_Float16)q1a.x, (_Float16)q1a.y};
    qh1[1] = h2{(_Float16)q1a.z, (_Float16)q1a.w};
    qh1[2] = h2{(_Float16)q1b.x, (_Float16)q1b.y};
    qh1[3] = h2{(_Float16)q1b.z, (_Float16)q1b.w};

    float ah0[8], ah1[8];
    #pragma unroll
    for (int c = 0; c < 8; ++c) {
        int t = quad * 8 + c;
        ah0[c] = dot8(q0a, q0b, relh + (t - h0q + 31) * 8);
        ah1[c] = dot8(q1a, q1b, relh + (t - h1q + 31) * 8);
    }

    __syncthreads();

    h2 acc0[4] = {h2{0,0}, h2{0,0}, h2{0,0}, h2{0,0}};
    h2 acc1[4] = {h2{0,0}, h2{0,0}, h2{0,0}, h2{0,0}};
    float l0 = 0.f, l1 = 0.f;

    for (int w2 = 0; w2 < 32; ++w2) {
        float aw0 = smem[w2 * 128 + lane];
        float aw1 = smem[w2 * 128 + 64 + lane];
        const unsigned int* sk = stg + w2 * 8;
        #pragma unroll
        for (int c = 0; c < 8; ++c) {
            KV16 ku, vu;
            ku.u = *(const uint4*)(sk + c * 256);       // key = c*32 + w2
            vu.u = *(const uint4*)(sk + c * 256 + 4);

            float s0 = aw0 + ah0[c];
            float s1 = aw1 + ah1[c];
            s0 = fdot2_acc(qh0[0], ku.h[0], s0);
            s0 = fdot2_acc(qh0[1], ku.h[1], s0);
            s0 = fdot2_acc(qh0[2], ku.h[2], s0);
            s0 = fdot2_acc(qh0[3], ku.h[3], s0);
            s1 = fdot2_acc(qh1[0], ku.h[0], s1);
            s1 = fdot2_acc(qh1[1], ku.h[1], s1);
            s1 = fdot2_acc(qh1[2], ku.h[2], s1);
            s1 = fdot2_acc(qh1[3], ku.h[3], s1);

            float pe0 = __expf(s0);
            float pe1 = __expf(s1);
            l0 += pe0; l1 += pe1;

            h2 p0 = h2{(_Float16)pe0, (_Float16)pe0};
            h2 p1 = h2{(_Float16)pe1, (_Float16)pe1};
            #pragma unroll
            for (int j = 0; j < 4; ++j) {
                acc0[j] += p0 * vu.h[j];   // v_pk_fma_f16
                acc1[j] += p1 * vu.h[j];
            }
        }
    }

    float f0[8], f1[8];
    #pragma unroll
    for (int j = 0; j < 4; ++j) {
        f0[2*j] = (float)acc0[j][0]; f0[2*j+1] = (float)acc0[j][1];
        f1[2*j] = (float)acc1[j][0]; f1[2*j+1] = (float)acc1[j][1];
    }

    __syncthreads();   // done with lAw/stage -> reuse as reduction buffer
    #pragma unroll
    for (int d = 0; d < 8; ++d) {
        smem[d * 256 + tid] = f0[d];
        smem[(9 + d) * 256 + tid] = f1[d];
    }
    smem[8 * 256 + tid] = l0;
    smem[17 * 256 + tid] = l1;
    __syncthreads();

    if (tid < 128) {
        int ln = tid & 63;
        int sb = (tid < 64) ? 0 : 9;
        float l = smem[(sb + 8) * 256 + ln]       + smem[(sb + 8) * 256 + ln + 64] +
                  smem[(sb + 8) * 256 + ln + 128] + smem[(sb + 8) * 256 + ln + 192];
        float inv = 1.0f / l;
        int b = bn >> 3, n = bn & 7;
        float* ap = apre + (b * 64 + n * 8) * 1024 + qcv * 128 + tid;
        #pragma unroll
        for (int d = 0; d < 8; ++d) {
            float av = smem[(sb + d) * 256 + ln]       + smem[(sb + d) * 256 + ln + 64] +
                       smem[(sb + d) * 256 + ln + 128] + smem[(sb + d) * 256 + ln + 192];
            ap[d * 1024] = av * inv;
        }
    }
}

// ---------------------------------------------------------------------------
// Kernel 3: fused output (f32). grid = 384 blocks:
//   blk < 128: 3x3 conv. b = blk>>4, og = blk&15, oc = og*4..+3.
//     Thread (rl = tid>>3: out row 0..31, cg = tid&7, c0 = cg*4): 4 cols x
//     4 oc. x staged per 8-channel chunk as [cc][34 r][35 c] (stride 35 keeps
//     window reads <=2-way banked), zero-padded on the fly from raw x.
//     Weights [ct][4g] b128 broadcast: one read serves 16 FMAs.
//   blk >= 128: attn 1x1 proj (as R10). b=(blk-128)>>5; rg, og in rem.
// ---------------------------------------------------------------------------
__global__ __launch_bounds__(256) void k_out(
    const float* __restrict__ x,
    const float* __restrict__ wconv,
    const float* __restrict__ bconv,
    const float* __restrict__ wattn,
    const float* __restrict__ battn,
    const float* __restrict__ apre,
    float* __restrict__ out)
{
    __shared__ __align__(16) float wl[2304];     // conv: [576 ct][4 g]
    __shared__ __align__(16) float xl[8 * 1190]; // conv: [8 cc][34 r][35 c]
    __shared__ float bl[8];

    int blk = blockIdx.x;
    int tid = threadIdx.x;

    if (blk < 128) {
        int b = blk >> 4, og = blk & 15;
        int oc0 = og * 4;
        for (int i = tid; i < 2304; i += 256) {
            int g = i & 3, ct = i >> 2;
            wl[i] = wconv[(oc0 + g) * 576 + ct];
        }
        if (tid < 4) bl[tid] = bconv[oc0 + tid];

        int rl = tid >> 3;                  // out row 0..31
        int c0 = (tid & 7) * 4;             // out col base
        float acc[4][4];                    // [oc][col]
        #pragma unroll
        for (int g = 0; g < 4; ++g)
            #pragma unroll
            for (int cix = 0; cix < 4; ++cix) acc[g][cix] = 0.f;

        const float* xsrc = x + b * 64 * 1024;

        for (int ch = 0; ch < 8; ++ch) {
            __syncthreads();                // prev readers done (+wl visible)
            for (int i = tid; i < 9520; i += 256) {
                int cc = i / 1190, r2 = i % 1190;
                int r = r2 / 35, cl = r2 % 35;
                int inr = r - 1, inc = cl - 1;
                float v = 0.f;
                if ((unsigned)inr < 32u && (unsigned)inc < 32u)
                    v = xsrc[(ch * 8 + cc) * 1024 + inr * 32 + inc];
                xl[i] = v;
            }
            __syncthreads();
            for (int cc = 0; cc < 8; ++cc) {
                const float* xc = xl + cc * 1190 + rl * 35 + c0;
                float xv[3][6];
                #pragma unroll
                for (int dr = 0; dr < 3; ++dr)
                    #pragma unroll
                    for (int dc = 0; dc < 6; ++dc)
                        xv[dr][dc] = xc[dr * 35 + dc];
                const float4* wc = (const float4*)wl + (ch * 8 + cc) * 9;
                #pragma unroll
                for (int t = 0; t < 9; ++t) {
                    float4 wv = wc[t];      // broadcast b128: 4 oc weights
                    int tr = t / 3, tc = t % 3;
                    #pragma unroll
                    for (int cix = 0; cix < 4; ++cix) {
                        float xs = xv[tr][tc + cix];
                        acc[0][cix] = fmaf(wv.x, xs, acc[0][cix]);
                        acc[1][cix] = fmaf(wv.y, xs, acc[1][cix]);
                        acc[2][cix] = fmaf(wv.z, xs, acc[2][cix]);
                        acc[3][cix] = fmaf(wv.w, xs, acc[3][cix]);
                    }
                }
            }
        }
        int p0 = rl * 32 + c0;
        #pragma unroll
        for (int g = 0; g < 4; ++g) {
            float4 o4 = make_float4(acc[g][0] + bl[g], acc[g][1] + bl[g],
                                    acc[g][2] + bl[g], acc[g][3] + bl[g]);
            *(float4*)(out + (b * 128 + oc0 + g) * 1024 + p0) = o4;
        }
    } else {
        int pb = blk - 128;
        int b = pb >> 5, rem = pb & 31, rg = rem >> 3, og = rem & 7;
        int o0 = og * 8;
        for (int i = tid; i < 512; i += 256) {
            int g = i & 7, c = i >> 3;
            wl[c * 8 + g] = wattn[(o0 + g) * 64 + c];
        }
        if (tid < 8) bl[tid] = battn[o0 + tid];
        __syncthreads();

        int p = rg * 256 + tid;
        float acc[8] = {0,0,0,0,0,0,0,0};
        const float* ap = apre + b * 65536 + p;
        #pragma unroll 4
        for (int c = 0; c < 64; ++c) {
            float xv = ap[c * 1024];
            const float4* wv4 = (const float4*)(wl + c * 8);
            float4 wa = wv4[0], wb = wv4[1];  // broadcast
            acc[0] = fmaf(wa.x, xv, acc[0]); acc[1] = fmaf(wa.y, xv, acc[1]);
            acc[2] = fmaf(wa.z, xv, acc[2]); acc[3] = fmaf(wa.w, xv, acc[3]);
            acc[4] = fmaf(wb.x, xv, acc[4]); acc[5] = fmaf(wb.y, xv, acc[5]);
            acc[6] = fmaf(wb.z, xv, acc[6]); acc[7] = fmaf(wb.w, xv, acc[7]);
        }
        #pragma unroll
        for (int g = 0; g < 8; ++g)
            out[(b * 128 + 64 + o0 + g) * 1024 + p] = acc[g] + bl[g];
    }
}

// ---------------------------------------------------------------------------
extern "C" void kernel_launch(void* const* d_in, const int* in_sizes, int n_in,
                              void* d_out, int out_size, void* d_ws, size_t ws_size,
                              hipStream_t stream)
{
    float* ws = (float*)d_ws;
    float* out = (float*)d_out;
    const float* x      = (const float*)d_in[0];
    const float* conv_w = (const float*)d_in[1];
    const float* conv_b = (const float*)d_in[2];
    const float* qkv_w  = (const float*)d_in[3];
    const float* qkv_b  = (const float*)d_in[4];
    const float* attn_w = (const float*)d_in[5];
    const float* attn_b = (const float*)d_in[6];
    const float* rel_w  = (const float*)d_in[7];
    const float* rel_h  = (const float*)d_in[8];

    k_qkv<<<512, 256, 0, stream>>>(
        x, qkv_w, qkv_b, ws + QBUF, (unsigned int*)(ws + KVBUF));
    k_attn<<<512, 256, 0, stream>>>(
        ws + QBUF, (const unsigned int*)(ws + KVBUF), rel_w, rel_h, ws + APRE);
    k_out<<<384, 256, 0, stream>>>(
        x, conv_w, conv_b, attn_w, attn_b, ws + APRE, out);
}

// Round 12
// 182.584 us; speedup vs baseline: 1.2504x; 1.2504x over previous
//
#include <hip/hip_runtime.h>
#include <hip/hip_bf16.h>
#include <hip/hip_fp16.h>

// Problem constants: B=8, IN_C=64, H=W=32, NH=8, dkh=dvh=8, OUT_C=128.
// Inputs: float32 storage (verified R1/R2). Output: float32.
//
// R11->R12: k_out conv reverted to the R10 256-block shape (16 rows/block,
// 2 cols x 4 oc per thread) -- R11's 128-block/4-col version collapsed to
// 1 block/CU (Occupancy 6.4%) and went latency-serial (117 us). Staging now
// zero-pads inline from raw x ([8cc][18r][35c], odd stride). k_prep stays
// deleted; k_qkv/k_attn unchanged from R11.

// ---- workspace layout (float32 element offsets) ----
constexpr int QBUF  = 0;                       // [64 bn][1024][8] f32 (q pre-scaled)
constexpr int KVBUF = 524288;                  // [64 bn][1024][8] uint (f16x2 k|v)
constexpr int APRE  = KVBUF + 524288;          // [8][64][1024]
// total 1.57M floats ~ 6.3 MB

typedef _Float16 h2 __attribute__((ext_vector_type(2)));

#if defined(__has_builtin)
#if __has_builtin(__builtin_amdgcn_fdot2)
#define HAVE_FDOT2 1
#endif
#endif

__device__ __forceinline__ float fdot2_acc(h2 a, h2 b, float c) {
#ifdef HAVE_FDOT2
    return __builtin_amdgcn_fdot2(a, b, c, false);
#else
    return c + (float)a[0] * (float)b[0] + (float)a[1] * (float)b[1];
#endif
}

__device__ __forceinline__ float dot8(float4 a, float4 b, const float* r) {
    return a.x*r[0] + a.y*r[1] + a.z*r[2] + a.w*r[3] +
           b.x*r[4] + b.y*r[5] + b.z*r[6] + b.w*r[7];
}

union KV16 { uint4 u; h2 h[4]; };
union PK16 { __half2 hh; unsigned int u; };

// ---------------------------------------------------------------------------
// Kernel 1: qkv 1x1 conv. grid = 8(b) x 4(pos chunk) x 16(out group of 12).
// Reads x directly (coalesced). Channel pairs stored immediately (no spill).
// Q stored f32 (scaled); K/V packed f16x2: dw 0..3 = k pairs, 4..7 = v pairs.
// ---------------------------------------------------------------------------
__global__ __launch_bounds__(256) void k_qkv(
    const float* __restrict__ x,
    const float* __restrict__ wq,
    const float* __restrict__ bq,
    float* __restrict__ qbuf,
    unsigned int* __restrict__ kvh)
{
    __shared__ __align__(16) float4 wl4[192];   // 12 rows x 16 float4
    __shared__ float bl[12];

    int blk = blockIdx.x;
    int b = blk >> 6, rem = blk & 63, pc = rem >> 4, og = rem & 15;
    int tid = threadIdx.x;

    if (tid < 192) wl4[tid] = ((const float4*)(wq + og * 768))[tid];
    if (tid < 12)  bl[tid] = bq[og * 12 + tid];

    int p = pc * 256 + tid;                // 0..1023
    const float* xb = x + (b * 64) * 1024 + p;
    float xr[64];
    #pragma unroll
    for (int c = 0; c < 64; ++c) xr[c] = xb[c * 1024];

    __syncthreads();

    for (int pr = 0; pr < 6; ++pr) {       // channel pair (2 chains live)
        int oo = pr * 2;
        float accA = bl[oo], accB = bl[oo + 1];
        #pragma unroll
        for (int c4 = 0; c4 < 16; ++c4) {
            float4 wa = wl4[oo * 16 + c4];        // LDS broadcast
            float4 wb = wl4[(oo + 1) * 16 + c4];
            accA = fmaf(wa.x, xr[c4 * 4 + 0], accA);
            accA = fmaf(wa.y, xr[c4 * 4 + 1], accA);
            accA = fmaf(wa.z, xr[c4 * 4 + 2], accA);
            accA = fmaf(wa.w, xr[c4 * 4 + 3], accA);
            accB = fmaf(wb.x, xr[c4 * 4 + 0], accB);
            accB = fmaf(wb.y, xr[c4 * 4 + 1], accB);
            accB = fmaf(wb.z, xr[c4 * 4 + 2], accB);
            accB = fmaf(wb.w, xr[c4 * 4 + 3], accB);
        }
        int o = og * 12 + oo;              // even; pair never straddles q/k/v
        if (o < 64) {
            float2 qv = make_float2(accA * 0.35355339059327373f,
                                    accB * 0.35355339059327373f);
            *(float2*)(qbuf + ((b * 8 + (o >> 3)) * 1024 + p) * 8 + (o & 7)) = qv;
        } else {
            PK16 pk;
            pk.hh = __floats2half2_rn(accA, accB);
            int idx;
            if (o < 128) {
                int kk = o - 64;
                idx = ((b * 8 + (kk >> 3)) * 1024 + p) * 8 + ((kk & 7) >> 1);
            } else {
                int vv = o - 128;
                idx = ((b * 8 + (vv >> 3)) * 1024 + p) * 8 + 4 + ((vv & 7) >> 1);
            }
            kvh[idx] = pk.u;
        }
    }
}

// ---------------------------------------------------------------------------
// Kernel 2: attention. grid = 64(bn) x 8(query chunk of 128) = 512 blocks.
// Thread (lane, quad) owns queries {iq0, iq0+64}; wave quad owns a 256-key
// quarter staged ONCE into LDS as f16 (8 KB/wave). Inner iter: 2x ds_read_b128
// + 8 fdot2 + 2 exp + 8 pk_fma_f16. Ah in regs; Aw LDS per 32 keys.
// rel tables read directly from inputs. No-max softmax (logits O(+-3)).
// ---------------------------------------------------------------------------
__global__ __launch_bounds__(256) void k_attn(
    const float* __restrict__ qbuf,
    const unsigned int* __restrict__ kvh,
    const float* __restrict__ relw,
    const float* __restrict__ relh,
    float* __restrict__ apre)
{
    // [0,4096): lAw[32][128]; [4096,12288): stage 4 waves x 2048 dwords.
    // After main loop, [0,4608) reused as reduction buffer.
    __shared__ __align__(16) float smem[12288];
    unsigned int* stageAll = (unsigned int*)(smem + 4096);

    int tid = threadIdx.x;
    int lane = tid & 63, quad = tid >> 6;
    int bn = blockIdx.x >> 3, qcv = blockIdx.x & 7;

    // ---- fill lAw: thread covers query qi = tid&127, rows (tid>>7)*16.. ----
    {
        int qi = tid & 127;
        int r0 = (tid >> 7) * 16;
        int iqf = qcv * 128 + qi;
        int wf = iqf & 31;
        const float* qpf = qbuf + (bn * 1024 + iqf) * 8;
        float4 fa = *(const float4*)qpf;
        float4 fb = *(const float4*)(qpf + 4);
        #pragma unroll
        for (int r = r0; r < r0 + 16; ++r)
            smem[r * 128 + qi] = dot8(fa, fb, relw + (r - wf + 31) * 8);
    }

    // ---- stage this wave's key quarter: 256 keys x 8 dwords (f16) ----
    unsigned int* stg = stageAll + quad * 2048;
    {
        const uint4* src = (const uint4*)(kvh + (bn * 1024 + quad * 256) * 8);
        uint4* dst = (uint4*)stg;
        #pragma unroll
        for (int i = 0; i < 8; ++i)
            dst[i * 64 + lane] = src[i * 64 + lane];
    }

    // ---- per-thread queries ----
    int iq0 = qcv * 128 + lane, iq1 = iq0 + 64;
    int h0q = iq0 >> 5, h1q = iq1 >> 5;
    const float* qp0 = qbuf + (bn * 1024 + iq0) * 8;
    const float* qp1 = qbuf + (bn * 1024 + iq1) * 8;
    float4 q0a = *(const float4*)qp0, q0b = *(const float4*)(qp0 + 4);
    float4 q1a = *(const float4*)qp1, q1b = *(const float4*)(qp1 + 4);

    h2 qh0[4], qh1[4];
    qh0[0] = h2{(_Float16)q0a.x, (_Float16)q0a.y};
    qh0[1] = h2{(_Float16)q0a.z, (_Float16)q0a.w};
    qh0[2] = h2{(_Float16)q0b.x, (_Float16)q0b.y};
    qh0[3] = h2{(_Float16)q0b.z, (_Float16)q0b.w};
    qh1[0] = h2{(_Float16)q1a.x, (_Float16)q1a.y};
    qh1[1] = h2{(_Float16)q1a.z, (_Float16)q1a.w};
    qh1[2] = h2{(_Float16)q1b.x, (_Float16)q1b.y};
    qh1[3] = h2{(_Float16)q1b.z, (_Float16)q1b.w};

    float ah0[8], ah1[8];
    #pragma unroll
    for (int c = 0; c < 8; ++c) {
        int t = quad * 8 + c;
        ah0[c] = dot8(q0a, q0b, relh + (t - h0q + 31) * 8);
        ah1[c] = dot8(q1a, q1b, relh + (t - h1q + 31) * 8);
    }

    __syncthreads();

    h2 acc0[4] = {h2{0,0}, h2{0,0}, h2{0,0}, h2{0,0}};
    h2 acc1[4] = {h2{0,0}, h2{0,0}, h2{0,0}, h2{0,0}};
    float l0 = 0.f, l1 = 0.f;

    for (int w2 = 0; w2 < 32; ++w2) {
        float aw0 = smem[w2 * 128 + lane];
        float aw1 = smem[w2 * 128 + 64 + lane];
        const unsigned int* sk = stg + w2 * 8;
        #pragma unroll
        for (int c = 0; c < 8; ++c) {
            KV16 ku, vu;
            ku.u = *(const uint4*)(sk + c * 256);       // key = c*32 + w2
            vu.u = *(const uint4*)(sk + c * 256 + 4);

            float s0 = aw0 + ah0[c];
            float s1 = aw1 + ah1[c];
            s0 = fdot2_acc(qh0[0], ku.h[0], s0);
            s0 = fdot2_acc(qh0[1], ku.h[1], s0);
            s0 = fdot2_acc(qh0[2], ku.h[2], s0);
            s0 = fdot2_acc(qh0[3], ku.h[3], s0);
            s1 = fdot2_acc(qh1[0], ku.h[0], s1);
            s1 = fdot2_acc(qh1[1], ku.h[1], s1);
            s1 = fdot2_acc(qh1[2], ku.h[2], s1);
            s1 = fdot2_acc(qh1[3], ku.h[3], s1);

            float pe0 = __expf(s0);
            float pe1 = __expf(s1);
            l0 += pe0; l1 += pe1;

            h2 p0 = h2{(_Float16)pe0, (_Float16)pe0};
            h2 p1 = h2{(_Float16)pe1, (_Float16)pe1};
            #pragma unroll
            for (int j = 0; j < 4; ++j) {
                acc0[j] += p0 * vu.h[j];   // v_pk_fma_f16
                acc1[j] += p1 * vu.h[j];
            }
        }
    }

    float f0[8], f1[8];
    #pragma unroll
    for (int j = 0; j < 4; ++j) {
        f0[2*j] = (float)acc0[j][0]; f0[2*j+1] = (float)acc0[j][1];
        f1[2*j] = (float)acc1[j][0]; f1[2*j+1] = (float)acc1[j][1];
    }

    __syncthreads();   // done with lAw/stage -> reuse as reduction buffer
    #pragma unroll
    for (int d = 0; d < 8; ++d) {
        smem[d * 256 + tid] = f0[d];
        smem[(9 + d) * 256 + tid] = f1[d];
    }
    smem[8 * 256 + tid] = l0;
    smem[17 * 256 + tid] = l1;
    __syncthreads();

    if (tid < 128) {
        int ln = tid & 63;
        int sb = (tid < 64) ? 0 : 9;
        float l = smem[(sb + 8) * 256 + ln]       + smem[(sb + 8) * 256 + ln + 64] +
                  smem[(sb + 8) * 256 + ln + 128] + smem[(sb + 8) * 256 + ln + 192];
        float inv = 1.0f / l;
        int b = bn >> 3, n = bn & 7;
        float* ap = apre + (b * 64 + n * 8) * 1024 + qcv * 128 + tid;
        #pragma unroll
        for (int d = 0; d < 8; ++d) {
            float av = smem[(sb + d) * 256 + ln]       + smem[(sb + d) * 256 + ln + 64] +
                       smem[(sb + d) * 256 + ln + 128] + smem[(sb + d) * 256 + ln + 192];
            ap[d * 1024] = av * inv;
        }
    }
}

// ---------------------------------------------------------------------------
// Kernel 3: fused output (f32). grid = 512 blocks:
//   blk < 256: 3x3 conv. b = blk>>5, rem = blk&31, rg = rem>>4 (16-row half),
//     og = rem&15, oc = og*4..+3. Thread (rl = tid>>4, colpair c0=(tid&15)*2):
//     2 cols x 4 oc. x staged per 8-channel chunk as [cc][18 r][35 c]
//     (odd stride -> <=2-way banks), zero-padded inline from raw x.
//     2 blocks/CU so one block's staging overlaps the other's compute.
//   blk >= 256: attn 1x1 proj; b=(blk-256)>>5; rg=rem>>3, og=rem&7.
// ---------------------------------------------------------------------------
__global__ __launch_bounds__(256) void k_out(
    const float* __restrict__ x,
    const float* __restrict__ wconv,
    const float* __restrict__ bconv,
    const float* __restrict__ wattn,
    const float* __restrict__ battn,
    const float* __restrict__ apre,
    float* __restrict__ out)
{
    __shared__ __align__(16) float wl[2304];     // conv: [576 ct][4 g]
    __shared__ __align__(16) float xl[8 * 630];  // conv: [8 cc][18 r][35 c]
    __shared__ float bl[8];

    int blk = blockIdx.x;
    int tid = threadIdx.x;

    if (blk < 256) {
        int b = blk >> 5, rem = blk & 31, rg = rem >> 4, og = rem & 15;
        int oc0 = og * 4;
        int R0 = rg * 16;                   // out-row base
        for (int i = tid; i < 2304; i += 256) {
            int g = i & 3, ct = i >> 2;
            wl[i] = wconv[(oc0 + g) * 576 + ct];
        }
        if (tid < 4) bl[tid] = bconv[oc0 + tid];

        int rl = tid >> 4;                  // local out row 0..15
        int c0 = (tid & 15) * 2;            // even col
        float acc0[4] = {0.f, 0.f, 0.f, 0.f};
        float acc1[4] = {0.f, 0.f, 0.f, 0.f};
        const float* xsrc = x + b * 64 * 1024;

        for (int ch = 0; ch < 8; ++ch) {
            __syncthreads();                // prev readers done (+wl visible)
            for (int i = tid; i < 5040; i += 256) {
                int cc = i / 630, r2 = i % 630;
                int r = r2 / 35, cl = r2 % 35;
                int inr = R0 + r - 1, inc = cl - 1;
                float v = 0.f;
                if ((unsigned)inr < 32u && (unsigned)inc < 32u)
                    v = xsrc[(ch * 8 + cc) * 1024 + inr * 32 + inc];
                xl[i] = v;
            }
            __syncthreads();
            for (int cc = 0; cc < 8; ++cc) {
                const float* xc = xl + cc * 630 + rl * 35 + c0;
                float xv[3][4];
                #pragma unroll
                for (int dr = 0; dr < 3; ++dr)
                    #pragma unroll
                    for (int dc = 0; dc < 4; ++dc)
                        xv[dr][dc] = xc[dr * 35 + dc];
                const float4* wc = (const float4*)wl + (ch * 8 + cc) * 9;
                #pragma unroll
                for (int t = 0; t < 9; ++t) {
                    float4 wv = wc[t];      // broadcast b128: 4 oc weights
                    float x0 = xv[t / 3][t % 3];
                    float x1 = xv[t / 3][t % 3 + 1];
                    acc0[0] = fmaf(wv.x, x0, acc0[0]); acc1[0] = fmaf(wv.x, x1, acc1[0]);
                    acc0[1] = fmaf(wv.y, x0, acc0[1]); acc1[1] = fmaf(wv.y, x1, acc1[1]);
                    acc0[2] = fmaf(wv.z, x0, acc0[2]); acc1[2] = fmaf(wv.z, x1, acc1[2]);
                    acc0[3] = fmaf(wv.w, x0, acc0[3]); acc1[3] = fmaf(wv.w, x1, acc1[3]);
                }
            }
        }
        int p0 = (R0 + rl) * 32 + c0;
        #pragma unroll
        for (int g = 0; g < 4; ++g) {
            float2 o2 = make_float2(acc0[g] + bl[g], acc1[g] + bl[g]);
            *(float2*)(out + (b * 128 + oc0 + g) * 1024 + p0) = o2;
        }
    } else {
        int pb = blk - 256;
        int b = pb >> 5, rem = pb & 31, rg = rem >> 3, og = rem & 7;
        int o0 = og * 8;
        for (int i = tid; i < 512; i += 256) {
            int g = i & 7, c = i >> 3;
            wl[c * 8 + g] = wattn[(o0 + g) * 64 + c];
        }
        if (tid < 8) bl[tid] = battn[o0 + tid];
        __syncthreads();

        int p = rg * 256 + tid;
        float acc[8] = {0,0,0,0,0,0,0,0};
        const float* ap = apre + b * 65536 + p;
        #pragma unroll 4
        for (int c = 0; c < 64; ++c) {
            float xv = ap[c * 1024];
            const float4* wv4 = (const float4*)(wl + c * 8);
            float4 wa = wv4[0], wb = wv4[1];  // broadcast
            acc[0] = fmaf(wa.x, xv, acc[0]); acc[1] = fmaf(wa.y, xv, acc[1]);
            acc[2] = fmaf(wa.z, xv, acc[2]); acc[3] = fmaf(wa.w, xv, acc[3]);
            acc[4] = fmaf(wb.x, xv, acc[4]); acc[5] = fmaf(wb.y, xv, acc[5]);
            acc[6] = fmaf(wb.z, xv, acc[6]); acc[7] = fmaf(wb.w, xv, acc[7]);
        }
        #pragma unroll
        for (int g = 0; g < 8; ++g)
            out[(b * 128 + 64 + o0 + g) * 1024 + p] = acc[g] + bl[g];
    }
}

// ---------------------------------------------------------------------------
extern "C" void kernel_launch(void* const* d_in, const int* in_sizes, int n_in,
                              void* d_out, int out_size, void* d_ws, size_t ws_size,
                              hipStream_t stream)
{
    float* ws = (float*)d_ws;
    float* out = (float*)d_out;
    const float* x      = (const float*)d_in[0];
    const float* conv_w = (const float*)d_in[1];
    const float* conv_b = (const float*)d_in[2];
    const float* qkv_w  = (const float*)d_in[3];
    const float* qkv_b  = (const float*)d_in[4];
    const float* attn_w = (const float*)d_in[5];
    const float* attn_b = (const float*)d_in[6];
    const float* rel_w  = (const float*)d_in[7];
    const float* rel_h  = (const float*)d_in[8];

    k_qkv<<<512, 256, 0, stream>>>(
        x, qkv_w, qkv_b, ws + QBUF, (unsigned int*)(ws + KVBUF));
    k_attn<<<512, 256, 0, stream>>>(
        ws + QBUF, (const unsigned int*)(ws + KVBUF), rel_w, rel_h, ws + APRE);
    k_out<<<512, 256, 0, stream>>>(
        x, conv_w, conv_b, attn_w, attn_b, ws + APRE, out);
}

// Round 13
// 148.493 us; speedup vs baseline: 1.5374x; 1.2296x over previous
//
#include <hip/hip_runtime.h>
#include <hip/hip_bf16.h>
#include <hip/hip_fp16.h>

// Problem constants: B=8, IN_C=64, H=W=32, NH=8, dkh=dvh=8, OUT_C=128.
// Inputs: float32 storage (verified R1/R2). Output: float32.
//
// R12->R13: k_out conv staging was serialized (stage-drain -> compute per
// chunk; 71.6 us vs ~25 us pipe floor, VALUBusy 16%). Now double-buffered:
// chunk c+1 global loads issued into registers BEFORE compute of chunk c,
// ds_write to alternate buffer after. Staging offsets precomputed once
// (no per-chunk divides). k_qkv/k_attn unchanged from R12.

// ---- workspace layout (float32 element offsets) ----
constexpr int QBUF  = 0;                       // [64 bn][1024][8] f32 (q pre-scaled)
constexpr int KVBUF = 524288;                  // [64 bn][1024][8] uint (f16x2 k|v)
constexpr int APRE  = KVBUF + 524288;          // [8][64][1024]
// total 1.57M floats ~ 6.3 MB

typedef _Float16 h2 __attribute__((ext_vector_type(2)));

#if defined(__has_builtin)
#if __has_builtin(__builtin_amdgcn_fdot2)
#define HAVE_FDOT2 1
#endif
#endif

__device__ __forceinline__ float fdot2_acc(h2 a, h2 b, float c) {
#ifdef HAVE_FDOT2
    return __builtin_amdgcn_fdot2(a, b, c, false);
#else
    return c + (float)a[0] * (float)b[0] + (float)a[1] * (float)b[1];
#endif
}

__device__ __forceinline__ float dot8(float4 a, float4 b, const float* r) {
    return a.x*r[0] + a.y*r[1] + a.z*r[2] + a.w*r[3] +
           b.x*r[4] + b.y*r[5] + b.z*r[6] + b.w*r[7];
}

union KV16 { uint4 u; h2 h[4]; };
union PK16 { __half2 hh; unsigned int u; };

// ---------------------------------------------------------------------------
// Kernel 1: qkv 1x1 conv. grid = 8(b) x 4(pos chunk) x 16(out group of 12).
// Reads x directly (coalesced). Channel pairs stored immediately (no spill).
// Q stored f32 (scaled); K/V packed f16x2: dw 0..3 = k pairs, 4..7 = v pairs.
// ---------------------------------------------------------------------------
__global__ __launch_bounds__(256) void k_qkv(
    const float* __restrict__ x,
    const float* __restrict__ wq,
    const float* __restrict__ bq,
    float* __restrict__ qbuf,
    unsigned int* __restrict__ kvh)
{
    __shared__ __align__(16) float4 wl4[192];   // 12 rows x 16 float4
    __shared__ float bl[12];

    int blk = blockIdx.x;
    int b = blk >> 6, rem = blk & 63, pc = rem >> 4, og = rem & 15;
    int tid = threadIdx.x;

    if (tid < 192) wl4[tid] = ((const float4*)(wq + og * 768))[tid];
    if (tid < 12)  bl[tid] = bq[og * 12 + tid];

    int p = pc * 256 + tid;                // 0..1023
    const float* xb = x + (b * 64) * 1024 + p;
    float xr[64];
    #pragma unroll
    for (int c = 0; c < 64; ++c) xr[c] = xb[c * 1024];

    __syncthreads();

    for (int pr = 0; pr < 6; ++pr) {       // channel pair (2 chains live)
        int oo = pr * 2;
        float accA = bl[oo], accB = bl[oo + 1];
        #pragma unroll
        for (int c4 = 0; c4 < 16; ++c4) {
            float4 wa = wl4[oo * 16 + c4];        // LDS broadcast
            float4 wb = wl4[(oo + 1) * 16 + c4];
            accA = fmaf(wa.x, xr[c4 * 4 + 0], accA);
            accA = fmaf(wa.y, xr[c4 * 4 + 1], accA);
            accA = fmaf(wa.z, xr[c4 * 4 + 2], accA);
            accA = fmaf(wa.w, xr[c4 * 4 + 3], accA);
            accB = fmaf(wb.x, xr[c4 * 4 + 0], accB);
            accB = fmaf(wb.y, xr[c4 * 4 + 1], accB);
            accB = fmaf(wb.z, xr[c4 * 4 + 2], accB);
            accB = fmaf(wb.w, xr[c4 * 4 + 3], accB);
        }
        int o = og * 12 + oo;              // even; pair never straddles q/k/v
        if (o < 64) {
            float2 qv = make_float2(accA * 0.35355339059327373f,
                                    accB * 0.35355339059327373f);
            *(float2*)(qbuf + ((b * 8 + (o >> 3)) * 1024 + p) * 8 + (o & 7)) = qv;
        } else {
            PK16 pk;
            pk.hh = __floats2half2_rn(accA, accB);
            int idx;
            if (o < 128) {
                int kk = o - 64;
                idx = ((b * 8 + (kk >> 3)) * 1024 + p) * 8 + ((kk & 7) >> 1);
            } else {
                int vv = o - 128;
                idx = ((b * 8 + (vv >> 3)) * 1024 + p) * 8 + 4 + ((vv & 7) >> 1);
            }
            kvh[idx] = pk.u;
        }
    }
}

// ---------------------------------------------------------------------------
// Kernel 2: attention. grid = 64(bn) x 8(query chunk of 128) = 512 blocks.
// Thread (lane, quad) owns queries {iq0, iq0+64}; wave quad owns a 256-key
// quarter staged ONCE into LDS as f16 (8 KB/wave). Inner iter: 2x ds_read_b128
// + 8 fdot2 + 2 exp + 8 pk_fma_f16. Ah in regs; Aw LDS per 32 keys.
// rel tables read directly from inputs. No-max softmax (logits O(+-3)).
// ---------------------------------------------------------------------------
__global__ __launch_bounds__(256) void k_attn(
    const float* __restrict__ qbuf,
    const unsigned int* __restrict__ kvh,
    const float* __restrict__ relw,
    const float* __restrict__ relh,
    float* __restrict__ apre)
{
    // [0,4096): lAw[32][128]; [4096,12288): stage 4 waves x 2048 dwords.
    // After main loop, [0,4608) reused as reduction buffer.
    __shared__ __align__(16) float smem[12288];
    unsigned int* stageAll = (unsigned int*)(smem + 4096);

    int tid = threadIdx.x;
    int lane = tid & 63, quad = tid >> 6;
    int bn = blockIdx.x >> 3, qcv = blockIdx.x & 7;

    // ---- fill lAw: thread covers query qi = tid&127, rows (tid>>7)*16.. ----
    {
        int qi = tid & 127;
        int r0 = (tid >> 7) * 16;
        int iqf = qcv * 128 + qi;
        int wf = iqf & 31;
        const float* qpf = qbuf + (bn * 1024 + iqf) * 8;
        float4 fa = *(const float4*)qpf;
        float4 fb = *(const float4*)(qpf + 4);
        #pragma unroll
        for (int r = r0; r < r0 + 16; ++r)
            smem[r * 128 + qi] = dot8(fa, fb, relw + (r - wf + 31) * 8);
    }

    // ---- stage this wave's key quarter: 256 keys x 8 dwords (f16) ----
    unsigned int* stg = stageAll + quad * 2048;
    {
        const uint4* src = (const uint4*)(kvh + (bn * 1024 + quad * 256) * 8);
        uint4* dst = (uint4*)stg;
        #pragma unroll
        for (int i = 0; i < 8; ++i)
            dst[i * 64 + lane] = src[i * 64 + lane];
    }

    // ---- per-thread queries ----
    int iq0 = qcv * 128 + lane, iq1 = iq0 + 64;
    int h0q = iq0 >> 5, h1q = iq1 >> 5;
    const float* qp0 = qbuf + (bn * 1024 + iq0) * 8;
    const float* qp1 = qbuf + (bn * 1024 + iq1) * 8;
    float4 q0a = *(const float4*)qp0, q0b = *(const float4*)(qp0 + 4);
    float4 q1a = *(const float4*)qp1, q1b = *(const float4*)(qp1 + 4);

    h2 qh0[4], qh1[4];
    qh0[0] = h2{(_Float16)q0a.x, (_Float16)q0a.y};
    qh0[1] = h2{(_Float16)q0a.z, (_Float16)q0a.w};
    qh0[2] = h2{(_Float16)q0b.x, (_Float16)q0b.y};
    qh0[3] = h2{(_Float16)q0b.z, (_Float16)q0b.w};
    qh1[0] = h2{(_Float16)q1a.x, (_Float16)q1a.y};
    qh1[1] = h2{(_Float16)q1a.z, (_Float16)q1a.w};
    qh1[2] = h2{(_Float16)q1b.x, (_Float16)q1b.y};
    qh1[3] = h2{(_Float16)q1b.z, (_Float16)q1b.w};

    float ah0[8], ah1[8];
    #pragma unroll
    for (int c = 0; c < 8; ++c) {
        int t = quad * 8 + c;
        ah0[c] = dot8(q0a, q0b, relh + (t - h0q + 31) * 8);
        ah1[c] = dot8(q1a, q1b, relh + (t - h1q + 31) * 8);
    }

    __syncthreads();

    h2 acc0[4] = {h2{0,0}, h2{0,0}, h2{0,0}, h2{0,0}};
    h2 acc1[4] = {h2{0,0}, h2{0,0}, h2{0,0}, h2{0,0}};
    float l0 = 0.f, l1 = 0.f;

    for (int w2 = 0; w2 < 32; ++w2) {
        float aw0 = smem[w2 * 128 + lane];
        float aw1 = smem[w2 * 128 + 64 + lane];
        const unsigned int* sk = stg + w2 * 8;
        #pragma unroll
        for (int c = 0; c < 8; ++c) {
            KV16 ku, vu;
            ku.u = *(const uint4*)(sk + c * 256);       // key = c*32 + w2
            vu.u = *(const uint4*)(sk + c * 256 + 4);

            float s0 = aw0 + ah0[c];
            float s1 = aw1 + ah1[c];
            s0 = fdot2_acc(qh0[0], ku.h[0], s0);
            s0 = fdot2_acc(qh0[1], ku.h[1], s0);
            s0 = fdot2_acc(qh0[2], ku.h[2], s0);
            s0 = fdot2_acc(qh0[3], ku.h[3], s0);
            s1 = fdot2_acc(qh1[0], ku.h[0], s1);
            s1 = fdot2_acc(qh1[1], ku.h[1], s1);
            s1 = fdot2_acc(qh1[2], ku.h[2], s1);
            s1 = fdot2_acc(qh1[3], ku.h[3], s1);

            float pe0 = __expf(s0);
            float pe1 = __expf(s1);
            l0 += pe0; l1 += pe1;

            h2 p0 = h2{(_Float16)pe0, (_Float16)pe0};
            h2 p1 = h2{(_Float16)pe1, (_Float16)pe1};
            #pragma unroll
            for (int j = 0; j < 4; ++j) {
                acc0[j] += p0 * vu.h[j];   // v_pk_fma_f16
                acc1[j] += p1 * vu.h[j];
            }
        }
    }

    float f0[8], f1[8];
    #pragma unroll
    for (int j = 0; j < 4; ++j) {
        f0[2*j] = (float)acc0[j][0]; f0[2*j+1] = (float)acc0[j][1];
        f1[2*j] = (float)acc1[j][0]; f1[2*j+1] = (float)acc1[j][1];
    }

    __syncthreads();   // done with lAw/stage -> reuse as reduction buffer
    #pragma unroll
    for (int d = 0; d < 8; ++d) {
        smem[d * 256 + tid] = f0[d];
        smem[(9 + d) * 256 + tid] = f1[d];
    }
    smem[8 * 256 + tid] = l0;
    smem[17 * 256 + tid] = l1;
    __syncthreads();

    if (tid < 128) {
        int ln = tid & 63;
        int sb = (tid < 64) ? 0 : 9;
        float l = smem[(sb + 8) * 256 + ln]       + smem[(sb + 8) * 256 + ln + 64] +
                  smem[(sb + 8) * 256 + ln + 128] + smem[(sb + 8) * 256 + ln + 192];
        float inv = 1.0f / l;
        int b = bn >> 3, n = bn & 7;
        float* ap = apre + (b * 64 + n * 8) * 1024 + qcv * 128 + tid;
        #pragma unroll
        for (int d = 0; d < 8; ++d) {
            float av = smem[(sb + d) * 256 + ln]       + smem[(sb + d) * 256 + ln + 64] +
                       smem[(sb + d) * 256 + ln + 128] + smem[(sb + d) * 256 + ln + 192];
            ap[d * 1024] = av * inv;
        }
    }
}

// ---------------------------------------------------------------------------
// Kernel 3: fused output (f32). grid = 512 blocks:
//   blk < 256: 3x3 conv, DOUBLE-BUFFERED staging. b=blk>>5, rg=(blk&31)>>4,
//     og=blk&15, oc=og*4..+3. Thread (rl=tid>>4, c0=(tid&15)*2): 2 cols x
//     4 oc. x tile [8cc][18r][35c] zero-padded inline; per-thread (offset,
//     valid) precomputed once; chunk c+1 loads issued before compute of c.
//   blk >= 256: attn 1x1 proj (unchanged).
// ---------------------------------------------------------------------------
__global__ __launch_bounds__(256) void k_out(
    const float* __restrict__ x,
    const float* __restrict__ wconv,
    const float* __restrict__ bconv,
    const float* __restrict__ wattn,
    const float* __restrict__ battn,
    const float* __restrict__ apre,
    float* __restrict__ out)
{
    __shared__ __align__(16) float wl[2304];      // conv: [576 ct][4 g]
    __shared__ __align__(16) float xl[2][5040];   // conv: 2 x [8cc][18r][35c]
    __shared__ float bl[8];

    int blk = blockIdx.x;
    int tid = threadIdx.x;

    if (blk < 256) {
        int b = blk >> 5, rem = blk & 31, rg = rem >> 4, og = rem & 15;
        int oc0 = og * 4;
        int R0 = rg * 16;                   // out-row base
        for (int i = tid; i < 2304; i += 256) {
            int g = i & 3, ct = i >> 2;
            wl[i] = wconv[(oc0 + g) * 576 + ct];
        }
        if (tid < 4) bl[tid] = bconv[oc0 + tid];

        const float* xsrc = x + b * 64 * 1024;

        // Precompute per-thread staging slots (fixed across chunks).
        int soff[20];
        #pragma unroll
        for (int j = 0; j < 20; ++j) {
            int i = tid + j * 256;
            int cc = i / 630, r2 = i % 630;
            int r = r2 / 35, cl = r2 % 35;
            int inr = R0 + r - 1, inc = cl - 1;
            bool inb = (i < 5040) && ((unsigned)inr < 32u) && ((unsigned)inc < 32u);
            soff[j] = inb ? (cc * 1024 + inr * 32 + inc) : -1;
        }

        float pf[20];
        // prologue: load + write chunk 0
        #pragma unroll
        for (int j = 0; j < 20; ++j)
            pf[j] = (soff[j] >= 0) ? xsrc[soff[j]] : 0.f;
        #pragma unroll
        for (int j = 0; j < 20; ++j) {
            int i = tid + j * 256;
            if (i < 5040) xl[0][i] = pf[j];
        }

        int rl = tid >> 4;                  // local out row 0..15
        int c0 = (tid & 15) * 2;            // even col
        float acc0[4] = {0.f, 0.f, 0.f, 0.f};
        float acc1[4] = {0.f, 0.f, 0.f, 0.f};

        for (int ch = 0; ch < 8; ++ch) {
            if (ch < 7) {                   // issue next chunk's loads EARLY
                const float* xs = xsrc + (ch + 1) * 8192;
                #pragma unroll
                for (int j = 0; j < 20; ++j)
                    pf[j] = (soff[j] >= 0) ? xs[soff[j]] : 0.f;
            }
            __syncthreads();                // xl[ch&1] visible to all
            const float* xbuf = xl[ch & 1];
            for (int cc = 0; cc < 8; ++cc) {
                const float* xc = xbuf + cc * 630 + rl * 35 + c0;
                float xv[3][4];
                #pragma unroll
                for (int dr = 0; dr < 3; ++dr)
                    #pragma unroll
                    for (int dc = 0; dc < 4; ++dc)
                        xv[dr][dc] = xc[dr * 35 + dc];
                const float4* wc = (const float4*)wl + (ch * 8 + cc) * 9;
                #pragma unroll
                for (int t = 0; t < 9; ++t) {
                    float4 wv = wc[t];      // broadcast b128: 4 oc weights
                    float x0 = xv[t / 3][t % 3];
                    float x1 = xv[t / 3][t % 3 + 1];
                    acc0[0] = fmaf(wv.x, x0, acc0[0]); acc1[0] = fmaf(wv.x, x1, acc1[0]);
                    acc0[1] = fmaf(wv.y, x0, acc0[1]); acc1[1] = fmaf(wv.y, x1, acc1[1]);
                    acc0[2] = fmaf(wv.z, x0, acc0[2]); acc1[2] = fmaf(wv.z, x1, acc1[2]);
                    acc0[3] = fmaf(wv.w, x0, acc0[3]); acc1[3] = fmaf(wv.w, x1, acc1[3]);
                }
            }
            if (ch < 7) {                   // write next chunk to other buffer
                float* xd = xl[(ch + 1) & 1];
                #pragma unroll
                for (int j = 0; j < 20; ++j) {
                    int i = tid + j * 256;
                    if (i < 5040) xd[i] = pf[j];
                }
            }
        }
        int p0 = (R0 + rl) * 32 + c0;
        #pragma unroll
        for (int g = 0; g < 4; ++g) {
            float2 o2 = make_float2(acc0[g] + bl[g], acc1[g] + bl[g]);
            *(float2*)(out + (b * 128 + oc0 + g) * 1024 + p0) = o2;
        }
    } else {
        int pb = blk - 256;
        int b = pb >> 5, rem = pb & 31, rg = rem >> 3, og = rem & 7;
        int o0 = og * 8;
        for (int i = tid; i < 512; i += 256) {
            int g = i & 7, c = i >> 3;
            wl[c * 8 + g] = wattn[(o0 + g) * 64 + c];
        }
        if (tid < 8) bl[tid] = battn[o0 + tid];
        __syncthreads();

        int p = rg * 256 + tid;
        float acc[8] = {0,0,0,0,0,0,0,0};
        const float* ap = apre + b * 65536 + p;
        #pragma unroll 4
        for (int c = 0; c < 64; ++c) {
            float xv = ap[c * 1024];
            const float4* wv4 = (const float4*)(wl + c * 8);
            float4 wa = wv4[0], wb = wv4[1];  // broadcast
            acc[0] = fmaf(wa.x, xv, acc[0]); acc[1] = fmaf(wa.y, xv, acc[1]);
            acc[2] = fmaf(wa.z, xv, acc[2]); acc[3] = fmaf(wa.w, xv, acc[3]);
            acc[4] = fmaf(wb.x, xv, acc[4]); acc[5] = fmaf(wb.y, xv, acc[5]);
            acc[6] = fmaf(wb.z, xv, acc[6]); acc[7] = fmaf(wb.w, xv, acc[7]);
        }
        #pragma unroll
        for (int g = 0; g < 8; ++g)
            out[(b * 128 + 64 + o0 + g) * 1024 + p] = acc[g] + bl[g];
    }
}

// ---------------------------------------------------------------------------
extern "C" void kernel_launch(void* const* d_in, const int* in_sizes, int n_in,
                              void* d_out, int out_size, void* d_ws, size_t ws_size,
                              hipStream_t stream)
{
    float* ws = (float*)d_ws;
    float* out = (float*)d_out;
    const float* x      = (const float*)d_in[0];
    const float* conv_w = (const float*)d_in[1];
    const float* conv_b = (const float*)d_in[2];
    const float* qkv_w  = (const float*)d_in[3];
    const float* qkv_b  = (const float*)d_in[4];
    const float* attn_w = (const float*)d_in[5];
    const float* attn_b = (const float*)d_in[6];
    const float* rel_w  = (const float*)d_in[7];
    const float* rel_h  = (const float*)d_in[8];

    k_qkv<<<512, 256, 0, stream>>>(
        x, qkv_w, qkv_b, ws + QBUF, (unsigned int*)(ws + KVBUF));
    k_attn<<<512, 256, 0, stream>>>(
        ws + QBUF, (const unsigned int*)(ws + KVBUF), rel_w, rel_h, ws + APRE);
    k_out<<<512, 256, 0, stream>>>(
        x, conv_w, conv_b, attn_w, attn_b, ws + APRE, out);
}